// Round 20
// baseline (335.278 us; speedup 1.0000x reference)
//
#include <hip/hip_runtime.h>
#include <hip/hip_bf16.h>
#include <stdint.h>

#define T_DIM 2048
#define B_DIM 4
#define E_DIM 1024
#define H_DIM 16
#define EHD 64
#define L2E 1.4426950408889634f
#define QSCALE (0.125f * L2E)
#define FMAXC 12.0f

typedef __attribute__((ext_vector_type(8))) short bf16x8;
typedef __attribute__((ext_vector_type(4))) float f32x4;
typedef __attribute__((ext_vector_type(16))) float f32x16;
typedef __attribute__((ext_vector_type(2))) float f32x2;
typedef __attribute__((ext_vector_type(2))) unsigned u32x2;
typedef __attribute__((ext_vector_type(4))) unsigned u32x4;

__device__ __forceinline__ unsigned short f2bf(float x) {
  unsigned int u = __builtin_bit_cast(unsigned int, x);
  u += 0x7fffu + ((u >> 16) & 1u);
  return (unsigned short)(u >> 16);
}

__device__ __forceinline__ unsigned pkbf(float a, float b) {
  return (unsigned)f2bf(a) | ((unsigned)f2bf(b) << 16);
}

// truncation pack (P hot path only; bias cancels in sum(pV)/sum(p))
__device__ __forceinline__ unsigned pk_trunc(float a, float b) {
  return (__builtin_bit_cast(unsigned, a) >> 16) |
         (__builtin_bit_cast(unsigned, b) & 0xffff0000u);
}

// expand packed bf16 pair (lo, hi) -> f32x2
__device__ __forceinline__ f32x2 bfpair1(unsigned w) {
  u32x2 u = {w << 16, w & 0xffff0000u};
  return __builtin_bit_cast(f32x2, u);
}

__device__ __forceinline__ void gload16(const void* g, void* l) {
  __builtin_amdgcn_global_load_lds(
      (const __attribute__((address_space(1))) void*)g,
      (__attribute__((address_space(3))) void*)l, 16, 0, 0);
}

// ---------------- fused fp32 -> bf16 for all 5 inputs (1 launch) ------------
__global__ __launch_bounds__(256) void cvt_fused(
    const float4* __restrict__ q, const float4* __restrict__ k,
    const float4* __restrict__ v, const float4* __restrict__ wqkv,
    const float4* __restrict__ wout, uint2* __restrict__ xq,
    uint2* __restrict__ xk, uint2* __restrict__ xv, uint2* __restrict__ wq,
    uint2* __restrict__ wo) {
  int i = blockIdx.x * 256 + threadIdx.x;
  const int stride = gridDim.x * 256;
  for (; i < 7340032; i += stride) {
    const float4* s;
    uint2* d;
    int j;
    if (i < 2097152) { s = q; d = xq; j = i; }
    else if (i < 4194304) { s = k; d = xk; j = i - 2097152; }
    else if (i < 6291456) { s = v; d = xv; j = i - 4194304; }
    else if (i < 7077888) { s = wqkv; d = wq; j = i - 6291456; }
    else { s = wout; d = wo; j = i - 7077888; }
    const float4 f = s[j];
    uint2 o;
    o.x = pkbf(f.x, f.y);
    o.y = pkbf(f.z, f.w);
    d[j] = o;
  }
}

// ---------------- mask fp32 -> bf16 permute, COALESCED READS ----------------
// Round 20: the old version gathered 2x float4 from 8KB-strided rows (~64
// lines/wave/2KB, 4x overfetch). Invert: each thread takes 8 CONSECUTIVE k
// of one q row (contiguous reads), and the permutation scatter moves to the
// WRITE side (uint2 8B writes, absorbed by L2 write-combining).
// Layout (unchanged): uint4 c = ((((qblk*32+t)*4+wave)*2+kb)*2+half)*64+lane;
// lane = hi*32+ql holds k = t*64+kb*32+half*16+hi*4+{0..3} in words (x,y) and
// k+8+{0..3} in words (z,w).
__global__ __launch_bounds__(256) void mask_perm(const float* __restrict__ mask,
                                                 uint2* __restrict__ out) {
  const int idx = blockIdx.x * 256 + threadIdx.x;  // 524288 threads, 8 k each
  const int q = idx >> 8;
  const int k = (idx & 255) * 8;
  const float4 a = *(const float4*)(mask + (size_t)q * T_DIM + k);
  const float4 b = *(const float4*)(mask + (size_t)q * T_DIM + k + 4);
  const int qblk = q >> 7, wave = (q >> 5) & 3, ql = q & 31;
  const int t = k >> 6, kb = (k >> 5) & 1, half = (k >> 4) & 1;
  const int rem8 = (k >> 3) & 1;  // 0: words (x,y); 1: words (z,w)
  const int cbase = ((((qblk * 32 + t) * 4 + wave) * 2 + kb) * 2 + half) * 64;
  // float4 a -> hi=0 lane (ql); float4 b -> hi=1 lane (32+ql)
  uint2 w0, w1;
  w0.x = pkbf(a.x, a.y);
  w0.y = pkbf(a.z, a.w);
  w1.x = pkbf(b.x, b.y);
  w1.y = pkbf(b.z, b.w);
  out[(size_t)(cbase + ql) * 2 + rem8] = w0;
  out[(size_t)(cbase + 32 + ql) * 2 + rem8] = w1;
}

// ---------------- 128x128 bf16 NT GEMM (m97 structure) ----------------
// MODE 0: QKV proj. Q third pre-scaled, row-major [bh][t][d].
//         K third -> fragment-permuted KP; V third -> fragment-permuted VP.
// MODE 1: out projection -> FP32 out[(t*B+b)*E + n].
template <int MODE>
__global__ __launch_bounds__(256) void gemm_kernel(
    const unsigned short* __restrict__ Abase,
    const unsigned short* __restrict__ Bt,
    const float* __restrict__ bias,
    void* __restrict__ outv, int K) {
  __shared__ alignas(16) short As[128 * 32];
  __shared__ alignas(16) short Bs[128 * 32];
  const int tid = threadIdx.x;
  const int lane = tid & 63, wave = tid >> 6;
  const int m0 = blockIdx.x * 128, n0 = blockIdx.y * 128;
  const int wr = wave >> 1, wc = wave & 1;
  const int lrow = lane & 15, lgrp = lane >> 4;

  const unsigned short* A = Abase;
  if (MODE == 0) A += (size_t)(n0 >> 10) * (8192u * 1024u);

  f32x4 acc[4][4];
#pragma unroll
  for (int m = 0; m < 4; ++m)
#pragma unroll
    for (int n = 0; n < 4; ++n) acc[m][n] = (f32x4){0.f, 0.f, 0.f, 0.f};

  const int srow = wave * 16 + (lane >> 2);
  const int scol = (lane & 3) * 8;
  short* lA0 = As + wave * 16 * 32;
  short* lA1 = As + (64 + wave * 16) * 32;
  short* lB0 = Bs + wave * 16 * 32;
  short* lB1 = Bs + (64 + wave * 16) * 32;

  for (int k0 = 0; k0 < K; k0 += 32) {
    const unsigned short* ga = A + (size_t)(m0 + srow) * K + k0 + scol;
    const unsigned short* gb = Bt + (size_t)(n0 + srow) * K + k0 + scol;
    gload16(ga, lA0);
    gload16(ga + (size_t)64 * K, lA1);
    gload16(gb, lB0);
    gload16(gb + (size_t)64 * K, lB1);
    __syncthreads();
    const short* pa = As + (wr * 64 + lrow) * 32 + lgrp * 8;
    const short* pb = Bs + (wc * 64 + lrow) * 32 + lgrp * 8;
    bf16x8 a[4], b[4];
#pragma unroll
    for (int m = 0; m < 4; ++m) a[m] = *(const bf16x8*)(pa + m * 512);
#pragma unroll
    for (int n = 0; n < 4; ++n) b[n] = *(const bf16x8*)(pb + n * 512);
#pragma unroll
    for (int m = 0; m < 4; ++m)
#pragma unroll
      for (int n = 0; n < 4; ++n)
        acc[m][n] = __builtin_amdgcn_mfma_f32_16x16x32_bf16(a[m], b[n], acc[m][n], 0, 0, 0);
    __syncthreads();
  }

#pragma unroll
  for (int n = 0; n < 4; ++n) {
    const int gn = n0 + wc * 64 + n * 16 + lrow;
    const float bv = bias[gn];
    if (MODE == 0) {
      unsigned short* out = (unsigned short*)outv;
      const int which = gn >> 10;
      const float qsc = (which == 0) ? QSCALE : 1.0f;
      const int e = gn & 1023;
      const int hh = e >> 6, dd = e & 63;
#pragma unroll
      for (int m = 0; m < 4; ++m)
#pragma unroll
        for (int r = 0; r < 4; ++r) {
          const int gm = m0 + wr * 64 + m * 16 + lgrp * 4 + r;
          const int t = gm >> 2, bb = gm & 3;  // A row index is t*B + b
          const unsigned short val = f2bf((acc[m][n][r] + bv) * qsc);
          const size_t rbase = ((size_t)which * 64 + bb * 16 + hh) * 131072;
          if (which == 0) {
            out[rbase + (size_t)t * 64 + dd] = val;
          } else if (which == 1) {
            out[rbase + (t >> 6) * 4096 +
                (((t >> 5) & 1) * 4 + (dd >> 4)) * 512 +
                ((((dd >> 3) & 1) << 5) + (t & 31)) * 8 + (dd & 7)] = val;
          } else {
            out[rbase + (t >> 6) * 4096 +
                ((dd >> 5) * 4 + ((t >> 4) & 3)) * 512 +
                ((((t >> 3) & 1) << 5) + (dd & 31)) * 8 + (t & 7)] = val;
          }
        }
    } else {
      float* out = (float*)outv;
#pragma unroll
      for (int m = 0; m < 4; ++m)
#pragma unroll
        for (int r = 0; r < 4; ++r) {
          const int gm = m0 + wr * 64 + m * 16 + lgrp * 4 + r;  // row = b*T + t
          const int bb = gm >> 11, t = gm & 2047;
          out[((size_t)t * B_DIM + bb) * E_DIM + gn] = acc[m][n][r] + bv;
        }
    }
  }
}

// ---------------- flash attention: 32x32 MFMA, mask in registers ------------
// grid (T/128, B*H), 4 waves x 32 q-rows (q = lane&31). Fixed-max softmax.
// Round 20: __launch_bounds__(256,4) -- VGPR 84 <= 128 cap, LDS 32KB allows
// 5 blocks/CU -> occupancy 3->4 blocks/CU for the VALU-leading kernel.
// Mask double-buffered in registers (round 19); P in-register via pk_trunc +
// v_permlane32_swap_b32 (round 18); K/V via linear global_load_lds from
// fragment-permuted global layouts (zero bank conflicts).
__global__ __launch_bounds__(256, 4) void attn_kernel(
    const unsigned short* __restrict__ Qm, const unsigned short* __restrict__ KPg,
    const unsigned short* __restrict__ VPg, const unsigned short* __restrict__ Mb,
    unsigned short* __restrict__ ctx) {
  __shared__ alignas(16) short Ks[2][4096];
  __shared__ alignas(16) short Vs[2][4096];
  const int tid = threadIdx.x, lane = tid & 63, wave = tid >> 6;
  const int ql = lane & 31, hi = lane >> 5;
  const int bh = blockIdx.y, b = bh >> 4, h = bh & 15;
  const int q0 = blockIdx.x * 128;
  const int qrow = q0 + wave * 32 + ql;

  const size_t base = (size_t)bh * (T_DIM * EHD);
  const uint4* mb4 = (const uint4*)Mb + (size_t)blockIdx.x * 32768 +
                     wave * 256 + lane;  // + tile*1024 + u*64

  bf16x8 qf[4];
#pragma unroll
  for (int i = 0; i < 4; ++i)
    qf[i] = *(const bf16x8*)(Qm + base + (size_t)qrow * 64 + i * 16 + hi * 8);

  f32x16 accO0 = {0.f, 0.f, 0.f, 0.f, 0.f, 0.f, 0.f, 0.f,
                  0.f, 0.f, 0.f, 0.f, 0.f, 0.f, 0.f, 0.f};
  f32x16 accO1 = accO0;
  f32x2 racc2 = {0.f, 0.f};

  uint4 mreg[2][4];  // [tile parity][u = kb*2+half] -- static indices

#define STAGE(bufi, T_)                                                         \
  {                                                                             \
    _Pragma("unroll") for (int s2 = 0; s2 < 2; ++s2) {                          \
      const int s = wave * 2 + s2;                                              \
      gload16(KPg + base + (size_t)(T_) * 4096 + s * 512 + lane * 8,            \
              &Ks[bufi][s * 512]);                                              \
      gload16(VPg + base + (size_t)(T_) * 4096 + s * 512 + lane * 8,            \
              &Vs[bufi][s * 512]);                                              \
    }                                                                           \
    _Pragma("unroll") for (int u = 0; u < 4; ++u) {                             \
      mreg[bufi][u] = mb4[(size_t)(T_) * 1024 + u * 64];                        \
    }                                                                           \
  }

// one mask word -> 2 p values of ACC regs (HALF*8+2W, +1); pack into wk
#define SOFTW(ACC, KB, HALF, W, MW)                                             \
  {                                                                             \
    const f32x2 mm = bfpair1(MW);                                               \
    const f32x2 sv = {ACC[HALF * 8 + 2 * W], ACC[HALF * 8 + 2 * W + 1]};        \
    const f32x2 tt =                                                            \
        __builtin_elementwise_fma(sv, mm, (f32x2){-FMAXC, -FMAXC});             \
    const float p0 = __builtin_amdgcn_exp2f(tt.x);                              \
    const float p1 = __builtin_amdgcn_exp2f(tt.y);                              \
    racc2 += (f32x2){p0, p1};                                                   \
    wk[KB][HALF * 4 + W] = pk_trunc(p0, p1);                                    \
  }

#define SOFTHALF(ACC, KB, HALF, MU)                                             \
  SOFTW(ACC, KB, HALF, 0, (MU).x)                                               \
  SOFTW(ACC, KB, HALF, 1, (MU).y)                                               \
  SOFTW(ACC, KB, HALF, 2, (MU).z)                                               \
  SOFTW(ACC, KB, HALF, 3, (MU).w)

// chunk (KB, HF): build PV B-frag via 2 permlane swaps, 2 MFMAs (dblk 0,1)
#define PVCHUNK(KB, HF)                                                         \
  {                                                                             \
    unsigned a0 = wk[KB][HF * 4 + 0], a1 = wk[KB][HF * 4 + 1];                  \
    unsigned a2 = wk[KB][HF * 4 + 2], a3 = wk[KB][HF * 4 + 3];                  \
    asm("v_permlane32_swap_b32 %0, %1" : "+v"(a0), "+v"(a2));                   \
    asm("v_permlane32_swap_b32 %0, %1" : "+v"(a1), "+v"(a3));                   \
    const u32x4 pw = {a0, a1, a2, a3};                                          \
    const bf16x8 pa = __builtin_bit_cast(bf16x8, pw);                           \
    const bf16x8 vf0 =                                                          \
        *(const bf16x8*)(vb + (0 + (KB)*2 + (HF)) * 512 + lane * 8);            \
    const bf16x8 vf1 =                                                          \
        *(const bf16x8*)(vb + (4 + (KB)*2 + (HF)) * 512 + lane * 8);            \
    accO0 = __builtin_amdgcn_mfma_f32_32x32x16_bf16(vf0, pa, accO0, 0, 0, 0);   \
    accO1 = __builtin_amdgcn_mfma_f32_32x32x16_bf16(vf1, pa, accO1, 0, 0, 0);   \
  }

#define ATTN_ITER(CUR, DO_PRE, TN)                                              \
  {                                                                             \
    if (DO_PRE) {                                                               \
      STAGE((CUR) ^ 1, TN);                                                     \
      __builtin_amdgcn_sched_barrier(0);                                        \
    }                                                                           \
    const short* kbl = Ks[CUR];                                                 \
    const short* vb = Vs[CUR];                                                  \
    f32x16 accS0 = {0.f, 0.f, 0.f, 0.f, 0.f, 0.f, 0.f, 0.f,                     \
                    0.f, 0.f, 0.f, 0.f, 0.f, 0.f, 0.f, 0.f};                    \
    f32x16 accS1 = accS0;                                                       \
    __builtin_amdgcn_s_setprio(1);                                              \
    _Pragma("unroll") for (int i = 0; i < 4; ++i) {                             \
      const bf16x8 kf = *(const bf16x8*)(kbl + i * 512 + lane * 8);             \
      accS0 = __builtin_amdgcn_mfma_f32_32x32x16_bf16(kf, qf[i], accS0, 0, 0, 0); \
    }                                                                           \
    _Pragma("unroll") for (int i = 0; i < 4; ++i) {                             \
      const bf16x8 kf = *(const bf16x8*)(kbl + (4 + i) * 512 + lane * 8);       \
      accS1 = __builtin_amdgcn_mfma_f32_32x32x16_bf16(kf, qf[i], accS1, 0, 0, 0); \
    }                                                                           \
    __builtin_amdgcn_s_setprio(0);                                              \
    unsigned wk[2][8];                                                          \
    SOFTHALF(accS0, 0, 0, mreg[CUR][0])                                         \
    SOFTHALF(accS0, 0, 1, mreg[CUR][1])                                         \
    SOFTHALF(accS1, 1, 0, mreg[CUR][2])                                         \
    SOFTHALF(accS1, 1, 1, mreg[CUR][3])                                         \
    __builtin_amdgcn_s_setprio(1);                                              \
    PVCHUNK(0, 0)                                                               \
    PVCHUNK(0, 1)                                                               \
    PVCHUNK(1, 0)                                                               \
    PVCHUNK(1, 1)                                                               \
    __builtin_amdgcn_s_setprio(0);                                              \
  }

#define WAITBAR                                                                 \
  asm volatile("s_waitcnt vmcnt(0)" ::: "memory");                              \
  __builtin_amdgcn_sched_barrier(0);                                            \
  __builtin_amdgcn_s_barrier();                                                 \
  __builtin_amdgcn_sched_barrier(0);

  STAGE(0, 0);
  WAITBAR

  for (int tt = 0; tt < 15; ++tt) {
    ATTN_ITER(0, 1, 2 * tt + 1);
    WAITBAR
    ATTN_ITER(1, 1, 2 * tt + 2);
    WAITBAR
  }
  ATTN_ITER(0, 1, 31);
  WAITBAR
  ATTN_ITER(1, 0, 0);

#undef ATTN_ITER
#undef WAITBAR
#undef STAGE
#undef PVCHUNK
#undef SOFTHALF
#undef SOFTW

  float racc = racc2.x + racc2.y;
  racc += __shfl_xor(racc, 32);
  const float inv = 1.f / racc;
  unsigned short* cp =
      ctx + ((size_t)b * T_DIM + qrow) * E_DIM + h * 64 + hi * 4;
#define EPI(ACC, DBLK)                                                          \
  _Pragma("unroll") for (int rg = 0; rg < 4; ++rg) {                            \
    uint2 w;                                                                    \
    w.x = pkbf(ACC[rg * 4 + 0] * inv, ACC[rg * 4 + 1] * inv);                   \
    w.y = pkbf(ACC[rg * 4 + 2] * inv, ACC[rg * 4 + 3] * inv);                   \
    *(uint2*)(cp + (DBLK)*32 + rg * 8) = w;                                     \
  }
  EPI(accO0, 0)
  EPI(accO1, 1)
#undef EPI
}

extern "C" void kernel_launch(void* const* d_in, const int* in_sizes, int n_in,
                              void* d_out, int out_size, void* d_ws, size_t ws_size,
                              hipStream_t stream) {
  const float* q    = (const float*)d_in[0];
  const float* k    = (const float*)d_in[1];
  const float* v    = (const float*)d_in[2];
  const float* mask = (const float*)d_in[3];
  const float* wqkv = (const float*)d_in[4];
  const float* bqkv = (const float*)d_in[5];
  const float* wout = (const float*)d_in[6];
  const float* bout = (const float*)d_in[7];

  char* ws = (char*)d_ws;
  unsigned short* Xb   = (unsigned short*)(ws);
  unsigned short* Wqb  = (unsigned short*)(ws + 50331648);
  unsigned short* Wob  = (unsigned short*)(ws + 56623104);
  unsigned short* QKVb = (unsigned short*)(ws + 58720256);  // [Q|KP|VP] bf16
  unsigned short* CTXb = (unsigned short*)(ws);             // [B][T][E] (Xb dead)
  unsigned short* Mb   = (unsigned short*)(ws + 16777216);  // permuted bf16 mask

  cvt_fused<<<2048, 256, 0, stream>>>(
      (const float4*)q, (const float4*)k, (const float4*)v,
      (const float4*)wqkv, (const float4*)wout, (uint2*)Xb,
      (uint2*)(Xb + 8388608), (uint2*)(Xb + 16777216), (uint2*)Wqb,
      (uint2*)Wob);

  gemm_kernel<0><<<dim3(64, 24), 256, 0, stream>>>(Xb, Wqb, bqkv, QKVb, 1024);
  // mask -> permuted bf16 AFTER GEMM1 (Mb lives in the then-dead Xb region)
  mask_perm<<<2048, 256, 0, stream>>>(mask, (uint2*)Mb);
  attn_kernel<<<dim3(16, 64), 256, 0, stream>>>(QKVb, QKVb + 8388608,
                                                QKVb + 16777216, Mb, CTXb);
  gemm_kernel<1><<<dim3(64, 8), 256, 0, stream>>>(CTXb, Wob, bout, d_out, 1024);
}

// Round 21
// 258.477 us; speedup vs baseline: 1.2971x; 1.2971x over previous
//
#include <hip/hip_runtime.h>
#include <hip/hip_bf16.h>
#include <stdint.h>

#define T_DIM 2048
#define B_DIM 4
#define E_DIM 1024
#define H_DIM 16
#define EHD 64
#define L2E 1.4426950408889634f
#define QSCALE (0.125f * L2E)
#define FMAXC 12.0f

typedef __attribute__((ext_vector_type(8))) short bf16x8;
typedef __attribute__((ext_vector_type(4))) float f32x4;
typedef __attribute__((ext_vector_type(16))) float f32x16;
typedef __attribute__((ext_vector_type(2))) float f32x2;
typedef __attribute__((ext_vector_type(2))) unsigned u32x2;
typedef __attribute__((ext_vector_type(4))) unsigned u32x4;

__device__ __forceinline__ unsigned short f2bf(float x) {
  unsigned int u = __builtin_bit_cast(unsigned int, x);
  u += 0x7fffu + ((u >> 16) & 1u);
  return (unsigned short)(u >> 16);
}

__device__ __forceinline__ unsigned pkbf(float a, float b) {
  return (unsigned)f2bf(a) | ((unsigned)f2bf(b) << 16);
}

// truncation pack (P hot path only; bias cancels in sum(pV)/sum(p))
__device__ __forceinline__ unsigned pk_trunc(float a, float b) {
  return (__builtin_bit_cast(unsigned, a) >> 16) |
         (__builtin_bit_cast(unsigned, b) & 0xffff0000u);
}

// expand packed bf16 pair (lo, hi) -> f32x2
__device__ __forceinline__ f32x2 bfpair1(unsigned w) {
  u32x2 u = {w << 16, w & 0xffff0000u};
  return __builtin_bit_cast(f32x2, u);
}

__device__ __forceinline__ void gload16(const void* g, void* l) {
  __builtin_amdgcn_global_load_lds(
      (const __attribute__((address_space(1))) void*)g,
      (__attribute__((address_space(3))) void*)l, 16, 0, 0);
}

// ---------------- fused fp32 -> bf16 for all 5 inputs (1 launch) ------------
__global__ __launch_bounds__(256) void cvt_fused(
    const float4* __restrict__ q, const float4* __restrict__ k,
    const float4* __restrict__ v, const float4* __restrict__ wqkv,
    const float4* __restrict__ wout, uint2* __restrict__ xq,
    uint2* __restrict__ xk, uint2* __restrict__ xv, uint2* __restrict__ wq,
    uint2* __restrict__ wo) {
  int i = blockIdx.x * 256 + threadIdx.x;
  const int stride = gridDim.x * 256;
  for (; i < 7340032; i += stride) {
    const float4* s;
    uint2* d;
    int j;
    if (i < 2097152) { s = q; d = xq; j = i; }
    else if (i < 4194304) { s = k; d = xk; j = i - 2097152; }
    else if (i < 6291456) { s = v; d = xv; j = i - 4194304; }
    else if (i < 7077888) { s = wqkv; d = wq; j = i - 6291456; }
    else { s = wout; d = wo; j = i - 7077888; }
    const float4 f = s[j];
    uint2 o;
    o.x = pkbf(f.x, f.y);
    o.y = pkbf(f.z, f.w);
    d[j] = o;
  }
}

// ---------------- mask fp32 -> bf16 permute, COALESCED READS ----------------
// Each thread takes 8 CONSECUTIVE k of one q row (contiguous reads); the
// permutation scatter is on the WRITE side (uint2 8B writes, L2-absorbed).
// Layout: uint4 c = ((((qblk*32+t)*4+wave)*2+kb)*2+half)*64+lane;
// lane = hi*32+ql holds k = t*64+kb*32+half*16+hi*4+{0..3} in words (x,y) and
// k+8+{0..3} in words (z,w).
__global__ __launch_bounds__(256) void mask_perm(const float* __restrict__ mask,
                                                 uint2* __restrict__ out) {
  const int idx = blockIdx.x * 256 + threadIdx.x;  // 524288 threads, 8 k each
  const int q = idx >> 8;
  const int k = (idx & 255) * 8;
  const float4 a = *(const float4*)(mask + (size_t)q * T_DIM + k);
  const float4 b = *(const float4*)(mask + (size_t)q * T_DIM + k + 4);
  const int qblk = q >> 7, wave = (q >> 5) & 3, ql = q & 31;
  const int t = k >> 6, kb = (k >> 5) & 1, half = (k >> 4) & 1;
  const int rem8 = (k >> 3) & 1;  // 0: words (x,y); 1: words (z,w)
  const int cbase = ((((qblk * 32 + t) * 4 + wave) * 2 + kb) * 2 + half) * 64;
  // float4 a -> hi=0 lane (ql); float4 b -> hi=1 lane (32+ql)
  uint2 w0, w1;
  w0.x = pkbf(a.x, a.y);
  w0.y = pkbf(a.z, a.w);
  w1.x = pkbf(b.x, b.y);
  w1.y = pkbf(b.z, b.w);
  out[(size_t)(cbase + ql) * 2 + rem8] = w0;
  out[(size_t)(cbase + 32 + ql) * 2 + rem8] = w1;
}

// ---------------- 128x128 bf16 NT GEMM (m97 structure) ----------------
// MODE 0: QKV proj. Q third pre-scaled, row-major [bh][t][d].
//         K third -> fragment-permuted KP; V third -> fragment-permuted VP.
// MODE 1: out projection -> FP32 out[(t*B+b)*E + n].
template <int MODE>
__global__ __launch_bounds__(256) void gemm_kernel(
    const unsigned short* __restrict__ Abase,
    const unsigned short* __restrict__ Bt,
    const float* __restrict__ bias,
    void* __restrict__ outv, int K) {
  __shared__ alignas(16) short As[128 * 32];
  __shared__ alignas(16) short Bs[128 * 32];
  const int tid = threadIdx.x;
  const int lane = tid & 63, wave = tid >> 6;
  const int m0 = blockIdx.x * 128, n0 = blockIdx.y * 128;
  const int wr = wave >> 1, wc = wave & 1;
  const int lrow = lane & 15, lgrp = lane >> 4;

  const unsigned short* A = Abase;
  if (MODE == 0) A += (size_t)(n0 >> 10) * (8192u * 1024u);

  f32x4 acc[4][4];
#pragma unroll
  for (int m = 0; m < 4; ++m)
#pragma unroll
    for (int n = 0; n < 4; ++n) acc[m][n] = (f32x4){0.f, 0.f, 0.f, 0.f};

  const int srow = wave * 16 + (lane >> 2);
  const int scol = (lane & 3) * 8;
  short* lA0 = As + wave * 16 * 32;
  short* lA1 = As + (64 + wave * 16) * 32;
  short* lB0 = Bs + wave * 16 * 32;
  short* lB1 = Bs + (64 + wave * 16) * 32;

  for (int k0 = 0; k0 < K; k0 += 32) {
    const unsigned short* ga = A + (size_t)(m0 + srow) * K + k0 + scol;
    const unsigned short* gb = Bt + (size_t)(n0 + srow) * K + k0 + scol;
    gload16(ga, lA0);
    gload16(ga + (size_t)64 * K, lA1);
    gload16(gb, lB0);
    gload16(gb + (size_t)64 * K, lB1);
    __syncthreads();
    const short* pa = As + (wr * 64 + lrow) * 32 + lgrp * 8;
    const short* pb = Bs + (wc * 64 + lrow) * 32 + lgrp * 8;
    bf16x8 a[4], b[4];
#pragma unroll
    for (int m = 0; m < 4; ++m) a[m] = *(const bf16x8*)(pa + m * 512);
#pragma unroll
    for (int n = 0; n < 4; ++n) b[n] = *(const bf16x8*)(pb + n * 512);
#pragma unroll
    for (int m = 0; m < 4; ++m)
#pragma unroll
      for (int n = 0; n < 4; ++n)
        acc[m][n] = __builtin_amdgcn_mfma_f32_16x16x32_bf16(a[m], b[n], acc[m][n], 0, 0, 0);
    __syncthreads();
  }

#pragma unroll
  for (int n = 0; n < 4; ++n) {
    const int gn = n0 + wc * 64 + n * 16 + lrow;
    const float bv = bias[gn];
    if (MODE == 0) {
      unsigned short* out = (unsigned short*)outv;
      const int which = gn >> 10;
      const float qsc = (which == 0) ? QSCALE : 1.0f;
      const int e = gn & 1023;
      const int hh = e >> 6, dd = e & 63;
#pragma unroll
      for (int m = 0; m < 4; ++m)
#pragma unroll
        for (int r = 0; r < 4; ++r) {
          const int gm = m0 + wr * 64 + m * 16 + lgrp * 4 + r;
          const int t = gm >> 2, bb = gm & 3;  // A row index is t*B + b
          const unsigned short val = f2bf((acc[m][n][r] + bv) * qsc);
          const size_t rbase = ((size_t)which * 64 + bb * 16 + hh) * 131072;
          if (which == 0) {
            out[rbase + (size_t)t * 64 + dd] = val;
          } else if (which == 1) {
            out[rbase + (t >> 6) * 4096 +
                (((t >> 5) & 1) * 4 + (dd >> 4)) * 512 +
                ((((dd >> 3) & 1) << 5) + (t & 31)) * 8 + (dd & 7)] = val;
          } else {
            out[rbase + (t >> 6) * 4096 +
                ((dd >> 5) * 4 + ((t >> 4) & 3)) * 512 +
                ((((t >> 3) & 1) << 5) + (dd & 31)) * 8 + (t & 7)] = val;
          }
        }
    } else {
      float* out = (float*)outv;
#pragma unroll
      for (int m = 0; m < 4; ++m)
#pragma unroll
        for (int r = 0; r < 4; ++r) {
          const int gm = m0 + wr * 64 + m * 16 + lgrp * 4 + r;  // row = b*T + t
          const int bb = gm >> 11, t = gm & 2047;
          out[((size_t)t * B_DIM + bb) * E_DIM + gn] = acc[m][n][r] + bv;
        }
    }
  }
}

// ---------------- flash attention: 32x32 MFMA, mask in registers ------------
// grid (T/128, B*H), 4 waves x 32 q-rows (q = lane&31). Fixed-max softmax.
// __launch_bounds__(256,3): VGPR floor is ~150 (round-20 lesson: forcing 4
// waves/SIMD caps VGPR at 128 -> SPILL, WRITE_SIZE 16->226MB, attn 113->189).
// Mask double-buffered in registers; P in-register via pk_trunc +
// v_permlane32_swap_b32; K/V via linear global_load_lds from
// fragment-permuted global layouts (zero bank conflicts).
__global__ __launch_bounds__(256, 3) void attn_kernel(
    const unsigned short* __restrict__ Qm, const unsigned short* __restrict__ KPg,
    const unsigned short* __restrict__ VPg, const unsigned short* __restrict__ Mb,
    unsigned short* __restrict__ ctx) {
  __shared__ alignas(16) short Ks[2][4096];
  __shared__ alignas(16) short Vs[2][4096];
  const int tid = threadIdx.x, lane = tid & 63, wave = tid >> 6;
  const int ql = lane & 31, hi = lane >> 5;
  const int bh = blockIdx.y, b = bh >> 4, h = bh & 15;
  const int q0 = blockIdx.x * 128;
  const int qrow = q0 + wave * 32 + ql;

  const size_t base = (size_t)bh * (T_DIM * EHD);
  const uint4* mb4 = (const uint4*)Mb + (size_t)blockIdx.x * 32768 +
                     wave * 256 + lane;  // + tile*1024 + u*64

  bf16x8 qf[4];
#pragma unroll
  for (int i = 0; i < 4; ++i)
    qf[i] = *(const bf16x8*)(Qm + base + (size_t)qrow * 64 + i * 16 + hi * 8);

  f32x16 accO0 = {0.f, 0.f, 0.f, 0.f, 0.f, 0.f, 0.f, 0.f,
                  0.f, 0.f, 0.f, 0.f, 0.f, 0.f, 0.f, 0.f};
  f32x16 accO1 = accO0;
  f32x2 racc2 = {0.f, 0.f};

  uint4 mreg[2][4];  // [tile parity][u = kb*2+half] -- static indices

#define STAGE(bufi, T_)                                                         \
  {                                                                             \
    _Pragma("unroll") for (int s2 = 0; s2 < 2; ++s2) {                          \
      const int s = wave * 2 + s2;                                              \
      gload16(KPg + base + (size_t)(T_) * 4096 + s * 512 + lane * 8,            \
              &Ks[bufi][s * 512]);                                              \
      gload16(VPg + base + (size_t)(T_) * 4096 + s * 512 + lane * 8,            \
              &Vs[bufi][s * 512]);                                              \
    }                                                                           \
    _Pragma("unroll") for (int u = 0; u < 4; ++u) {                             \
      mreg[bufi][u] = mb4[(size_t)(T_) * 1024 + u * 64];                        \
    }                                                                           \
  }

// one mask word -> 2 p values of ACC regs (HALF*8+2W, +1); pack into wk
#define SOFTW(ACC, KB, HALF, W, MW)                                             \
  {                                                                             \
    const f32x2 mm = bfpair1(MW);                                               \
    const f32x2 sv = {ACC[HALF * 8 + 2 * W], ACC[HALF * 8 + 2 * W + 1]};        \
    const f32x2 tt =                                                            \
        __builtin_elementwise_fma(sv, mm, (f32x2){-FMAXC, -FMAXC});             \
    const float p0 = __builtin_amdgcn_exp2f(tt.x);                              \
    const float p1 = __builtin_amdgcn_exp2f(tt.y);                              \
    racc2 += (f32x2){p0, p1};                                                   \
    wk[KB][HALF * 4 + W] = pk_trunc(p0, p1);                                    \
  }

#define SOFTHALF(ACC, KB, HALF, MU)                                             \
  SOFTW(ACC, KB, HALF, 0, (MU).x)                                               \
  SOFTW(ACC, KB, HALF, 1, (MU).y)                                               \
  SOFTW(ACC, KB, HALF, 2, (MU).z)                                               \
  SOFTW(ACC, KB, HALF, 3, (MU).w)

// chunk (KB, HF): build PV B-frag via 2 permlane swaps, 2 MFMAs (dblk 0,1)
#define PVCHUNK(KB, HF)                                                         \
  {                                                                             \
    unsigned a0 = wk[KB][HF * 4 + 0], a1 = wk[KB][HF * 4 + 1];                  \
    unsigned a2 = wk[KB][HF * 4 + 2], a3 = wk[KB][HF * 4 + 3];                  \
    asm("v_permlane32_swap_b32 %0, %1" : "+v"(a0), "+v"(a2));                   \
    asm("v_permlane32_swap_b32 %0, %1" : "+v"(a1), "+v"(a3));                   \
    const u32x4 pw = {a0, a1, a2, a3};                                          \
    const bf16x8 pa = __builtin_bit_cast(bf16x8, pw);                           \
    const bf16x8 vf0 =                                                          \
        *(const bf16x8*)(vb + (0 + (KB)*2 + (HF)) * 512 + lane * 8);            \
    const bf16x8 vf1 =                                                          \
        *(const bf16x8*)(vb + (4 + (KB)*2 + (HF)) * 512 + lane * 8);            \
    accO0 = __builtin_amdgcn_mfma_f32_32x32x16_bf16(vf0, pa, accO0, 0, 0, 0);   \
    accO1 = __builtin_amdgcn_mfma_f32_32x32x16_bf16(vf1, pa, accO1, 0, 0, 0);   \
  }

#define ATTN_ITER(CUR, DO_PRE, TN)                                              \
  {                                                                             \
    if (DO_PRE) {                                                               \
      STAGE((CUR) ^ 1, TN);                                                     \
      __builtin_amdgcn_sched_barrier(0);                                        \
    }                                                                           \
    const short* kbl = Ks[CUR];                                                 \
    const short* vb = Vs[CUR];                                                  \
    f32x16 accS0 = {0.f, 0.f, 0.f, 0.f, 0.f, 0.f, 0.f, 0.f,                     \
                    0.f, 0.f, 0.f, 0.f, 0.f, 0.f, 0.f, 0.f};                    \
    f32x16 accS1 = accS0;                                                       \
    __builtin_amdgcn_s_setprio(1);                                              \
    _Pragma("unroll") for (int i = 0; i < 4; ++i) {                             \
      const bf16x8 kf = *(const bf16x8*)(kbl + i * 512 + lane * 8);             \
      accS0 = __builtin_amdgcn_mfma_f32_32x32x16_bf16(kf, qf[i], accS0, 0, 0, 0); \
    }                                                                           \
    _Pragma("unroll") for (int i = 0; i < 4; ++i) {                             \
      const bf16x8 kf = *(const bf16x8*)(kbl + (4 + i) * 512 + lane * 8);       \
      accS1 = __builtin_amdgcn_mfma_f32_32x32x16_bf16(kf, qf[i], accS1, 0, 0, 0); \
    }                                                                           \
    __builtin_amdgcn_s_setprio(0);                                              \
    unsigned wk[2][8];                                                          \
    SOFTHALF(accS0, 0, 0, mreg[CUR][0])                                         \
    SOFTHALF(accS0, 0, 1, mreg[CUR][1])                                         \
    SOFTHALF(accS1, 1, 0, mreg[CUR][2])                                         \
    SOFTHALF(accS1, 1, 1, mreg[CUR][3])                                         \
    __builtin_amdgcn_s_setprio(1);                                              \
    PVCHUNK(0, 0)                                                               \
    PVCHUNK(0, 1)                                                               \
    PVCHUNK(1, 0)                                                               \
    PVCHUNK(1, 1)                                                               \
    __builtin_amdgcn_s_setprio(0);                                              \
  }

#define WAITBAR                                                                 \
  asm volatile("s_waitcnt vmcnt(0)" ::: "memory");                              \
  __builtin_amdgcn_sched_barrier(0);                                            \
  __builtin_amdgcn_s_barrier();                                                 \
  __builtin_amdgcn_sched_barrier(0);

  STAGE(0, 0);
  WAITBAR

  for (int tt = 0; tt < 15; ++tt) {
    ATTN_ITER(0, 1, 2 * tt + 1);
    WAITBAR
    ATTN_ITER(1, 1, 2 * tt + 2);
    WAITBAR
  }
  ATTN_ITER(0, 1, 31);
  WAITBAR
  ATTN_ITER(1, 0, 0);

#undef ATTN_ITER
#undef WAITBAR
#undef STAGE
#undef PVCHUNK
#undef SOFTHALF
#undef SOFTW

  float racc = racc2.x + racc2.y;
  racc += __shfl_xor(racc, 32);
  const float inv = 1.f / racc;
  unsigned short* cp =
      ctx + ((size_t)b * T_DIM + qrow) * E_DIM + h * 64 + hi * 4;
#define EPI(ACC, DBLK)                                                          \
  _Pragma("unroll") for (int rg = 0; rg < 4; ++rg) {                            \
    uint2 w;                                                                    \
    w.x = pkbf(ACC[rg * 4 + 0] * inv, ACC[rg * 4 + 1] * inv);                   \
    w.y = pkbf(ACC[rg * 4 + 2] * inv, ACC[rg * 4 + 3] * inv);                   \
    *(uint2*)(cp + (DBLK)*32 + rg * 8) = w;                                     \
  }
  EPI(accO0, 0)
  EPI(accO1, 1)
#undef EPI
}

extern "C" void kernel_launch(void* const* d_in, const int* in_sizes, int n_in,
                              void* d_out, int out_size, void* d_ws, size_t ws_size,
                              hipStream_t stream) {
  const float* q    = (const float*)d_in[0];
  const float* k    = (const float*)d_in[1];
  const float* v    = (const float*)d_in[2];
  const float* mask = (const float*)d_in[3];
  const float* wqkv = (const float*)d_in[4];
  const float* bqkv = (const float*)d_in[5];
  const float* wout = (const float*)d_in[6];
  const float* bout = (const float*)d_in[7];

  char* ws = (char*)d_ws;
  unsigned short* Xb   = (unsigned short*)(ws);
  unsigned short* Wqb  = (unsigned short*)(ws + 50331648);
  unsigned short* Wob  = (unsigned short*)(ws + 56623104);
  unsigned short* QKVb = (unsigned short*)(ws + 58720256);  // [Q|KP|VP] bf16
  unsigned short* CTXb = (unsigned short*)(ws);             // [B][T][E] (Xb dead)
  unsigned short* Mb   = (unsigned short*)(ws + 16777216);  // permuted bf16 mask

  cvt_fused<<<2048, 256, 0, stream>>>(
      (const float4*)q, (const float4*)k, (const float4*)v,
      (const float4*)wqkv, (const float4*)wout, (uint2*)Xb,
      (uint2*)(Xb + 8388608), (uint2*)(Xb + 16777216), (uint2*)Wqb,
      (uint2*)Wob);

  gemm_kernel<0><<<dim3(64, 24), 256, 0, stream>>>(Xb, Wqb, bqkv, QKVb, 1024);
  // mask -> permuted bf16 AFTER GEMM1 (Mb lives in the then-dead Xb region)
  mask_perm<<<2048, 256, 0, stream>>>(mask, (uint2*)Mb);
  attn_kernel<<<dim3(16, 64), 256, 0, stream>>>(QKVb, QKVb + 8388608,
                                                QKVb + 16777216, Mb, CTXb);
  gemm_kernel<1><<<dim3(64, 8), 256, 0, stream>>>(CTXb, Wob, bout, d_out, 1024);
}

// Round 22
// 238.014 us; speedup vs baseline: 1.4086x; 1.0860x over previous
//
#include <hip/hip_runtime.h>
#include <hip/hip_bf16.h>
#include <stdint.h>

#define T_DIM 2048
#define B_DIM 4
#define E_DIM 1024
#define H_DIM 16
#define EHD 64
#define L2E 1.4426950408889634f
#define QSCALE (0.125f * L2E)
#define FMAXC 12.0f

typedef __attribute__((ext_vector_type(8))) short bf16x8;
typedef __attribute__((ext_vector_type(4))) float f32x4;
typedef __attribute__((ext_vector_type(16))) float f32x16;
typedef __attribute__((ext_vector_type(2))) float f32x2;
typedef __attribute__((ext_vector_type(2))) unsigned u32x2;
typedef __attribute__((ext_vector_type(4))) unsigned u32x4;

__device__ __forceinline__ unsigned short f2bf(float x) {
  unsigned int u = __builtin_bit_cast(unsigned int, x);
  u += 0x7fffu + ((u >> 16) & 1u);
  return (unsigned short)(u >> 16);
}

__device__ __forceinline__ unsigned pkbf(float a, float b) {
  return (unsigned)f2bf(a) | ((unsigned)f2bf(b) << 16);
}

// truncation pack (P hot path only; bias cancels in sum(pV)/sum(p))
__device__ __forceinline__ unsigned pk_trunc(float a, float b) {
  return (__builtin_bit_cast(unsigned, a) >> 16) |
         (__builtin_bit_cast(unsigned, b) & 0xffff0000u);
}

// expand packed bf16 pair (lo, hi) -> f32x2
__device__ __forceinline__ f32x2 bfpair1(unsigned w) {
  u32x2 u = {w << 16, w & 0xffff0000u};
  return __builtin_bit_cast(f32x2, u);
}

__device__ __forceinline__ void gload16(const void* g, void* l) {
  __builtin_amdgcn_global_load_lds(
      (const __attribute__((address_space(1))) void*)g,
      (__attribute__((address_space(3))) void*)l, 16, 0, 0);
}

// ---------------- fused fp32 -> bf16 for all 5 inputs (1 launch) ------------
__global__ __launch_bounds__(256) void cvt_fused(
    const float4* __restrict__ q, const float4* __restrict__ k,
    const float4* __restrict__ v, const float4* __restrict__ wqkv,
    const float4* __restrict__ wout, uint2* __restrict__ xq,
    uint2* __restrict__ xk, uint2* __restrict__ xv, uint2* __restrict__ wq,
    uint2* __restrict__ wo) {
  int i = blockIdx.x * 256 + threadIdx.x;
  const int stride = gridDim.x * 256;
  for (; i < 7340032; i += stride) {
    const float4* s;
    uint2* d;
    int j;
    if (i < 2097152) { s = q; d = xq; j = i; }
    else if (i < 4194304) { s = k; d = xk; j = i - 2097152; }
    else if (i < 6291456) { s = v; d = xv; j = i - 4194304; }
    else if (i < 7077888) { s = wqkv; d = wq; j = i - 6291456; }
    else { s = wout; d = wo; j = i - 7077888; }
    const float4 f = s[j];
    uint2 o;
    o.x = pkbf(f.x, f.y);
    o.y = pkbf(f.z, f.w);
    d[j] = o;
  }
}

// ---------------- mask fp32 -> bf16 permute, COALESCED READS ----------------
__global__ __launch_bounds__(256) void mask_perm(const float* __restrict__ mask,
                                                 uint2* __restrict__ out) {
  const int idx = blockIdx.x * 256 + threadIdx.x;  // 524288 threads, 8 k each
  const int q = idx >> 8;
  const int k = (idx & 255) * 8;
  const float4 a = *(const float4*)(mask + (size_t)q * T_DIM + k);
  const float4 b = *(const float4*)(mask + (size_t)q * T_DIM + k + 4);
  const int qblk = q >> 7, wave = (q >> 5) & 3, ql = q & 31;
  const int t = k >> 6, kb = (k >> 5) & 1, half = (k >> 4) & 1;
  const int rem8 = (k >> 3) & 1;  // 0: words (x,y); 1: words (z,w)
  const int cbase = ((((qblk * 32 + t) * 4 + wave) * 2 + kb) * 2 + half) * 64;
  uint2 w0, w1;
  w0.x = pkbf(a.x, a.y);
  w0.y = pkbf(a.z, a.w);
  w1.x = pkbf(b.x, b.y);
  w1.y = pkbf(b.z, b.w);
  out[(size_t)(cbase + ql) * 2 + rem8] = w0;
  out[(size_t)(cbase + 32 + ql) * 2 + rem8] = w1;
}

// ---------------- 128x128 bf16 NT GEMM, BK=64 swizzled ----------------------
// Round 22: BK 32->64 halves the barrier count (the m97 structure's ~20%
// drain overhead). Staging: 4 issues x 32 rows per matrix, source col
// pre-swizzled ((lane&7)^(lane>>3))*8 (G21 involution); LDS stays linear.
// Reads: granule ((kk*4+lgrp)^(lrow&7)) -> conflict-free b128 (banks distinct
// across lrow 0..7, 2-way over 16 lanes = free). Two K-subtile compute halves
// per barrier span keep transient fragment VGPR identical to BK=32.
// MODE 0: QKV proj (Q pre-scaled row-major; K,V fragment-permuted).
// MODE 1: out projection -> FP32 out[(t*B+b)*E + n].
template <int MODE>
__global__ __launch_bounds__(256) void gemm_kernel(
    const unsigned short* __restrict__ Abase,
    const unsigned short* __restrict__ Bt,
    const float* __restrict__ bias,
    void* __restrict__ outv, int K) {
  __shared__ alignas(16) short As[128 * 64];
  __shared__ alignas(16) short Bs[128 * 64];
  const int tid = threadIdx.x;
  const int lane = tid & 63, wave = tid >> 6;
  const int m0 = blockIdx.x * 128, n0 = blockIdx.y * 128;
  const int wr = wave >> 1, wc = wave & 1;
  const int lrow = lane & 15, lgrp = lane >> 4;

  const unsigned short* A = Abase;
  if (MODE == 0) A += (size_t)(n0 >> 10) * (8192u * 1024u);

  f32x4 acc[4][4];
#pragma unroll
  for (int m = 0; m < 4; ++m)
#pragma unroll
    for (int n = 0; n < 4; ++n) acc[m][n] = (f32x4){0.f, 0.f, 0.f, 0.f};

  const int rr8 = lane >> 3;
  const int gc8 = ((lane & 7) ^ rr8) * 8;  // pre-swizzled source col (shorts)
  const int rsw = lrow & 7;                // read-side swizzle key

  for (int k0 = 0; k0 < K; k0 += 64) {
#pragma unroll
    for (int i = 0; i < 4; ++i) {
      const int row = i * 32 + wave * 8;
      gload16(A + (size_t)(m0 + row + rr8) * K + k0 + gc8, &As[row * 64]);
      gload16(Bt + (size_t)(n0 + row + rr8) * K + k0 + gc8, &Bs[row * 64]);
    }
    __syncthreads();
#pragma unroll
    for (int kk = 0; kk < 2; ++kk) {
      const int cg = (((kk * 4 + lgrp) ^ rsw)) * 8;
      const short* pa = As + (wr * 64 + lrow) * 64 + cg;
      const short* pb = Bs + (wc * 64 + lrow) * 64 + cg;
      bf16x8 a[4], b[4];
#pragma unroll
      for (int m = 0; m < 4; ++m) a[m] = *(const bf16x8*)(pa + m * 1024);
#pragma unroll
      for (int n = 0; n < 4; ++n) b[n] = *(const bf16x8*)(pb + n * 1024);
#pragma unroll
      for (int m = 0; m < 4; ++m)
#pragma unroll
        for (int n = 0; n < 4; ++n)
          acc[m][n] =
              __builtin_amdgcn_mfma_f32_16x16x32_bf16(a[m], b[n], acc[m][n], 0, 0, 0);
    }
    __syncthreads();
  }

#pragma unroll
  for (int n = 0; n < 4; ++n) {
    const int gn = n0 + wc * 64 + n * 16 + lrow;
    const float bv = bias[gn];
    if (MODE == 0) {
      unsigned short* out = (unsigned short*)outv;
      const int which = gn >> 10;
      const float qsc = (which == 0) ? QSCALE : 1.0f;
      const int e = gn & 1023;
      const int hh = e >> 6, dd = e & 63;
#pragma unroll
      for (int m = 0; m < 4; ++m)
#pragma unroll
        for (int r = 0; r < 4; ++r) {
          const int gm = m0 + wr * 64 + m * 16 + lgrp * 4 + r;
          const int t = gm >> 2, bb = gm & 3;  // A row index is t*B + b
          const unsigned short val = f2bf((acc[m][n][r] + bv) * qsc);
          const size_t rbase = ((size_t)which * 64 + bb * 16 + hh) * 131072;
          if (which == 0) {
            out[rbase + (size_t)t * 64 + dd] = val;
          } else if (which == 1) {
            out[rbase + (t >> 6) * 4096 +
                (((t >> 5) & 1) * 4 + (dd >> 4)) * 512 +
                ((((dd >> 3) & 1) << 5) + (t & 31)) * 8 + (dd & 7)] = val;
          } else {
            out[rbase + (t >> 6) * 4096 +
                ((dd >> 5) * 4 + ((t >> 4) & 3)) * 512 +
                ((((t >> 3) & 1) << 5) + (dd & 31)) * 8 + (t & 7)] = val;
          }
        }
    } else {
      float* out = (float*)outv;
#pragma unroll
      for (int m = 0; m < 4; ++m)
#pragma unroll
        for (int r = 0; r < 4; ++r) {
          const int gm = m0 + wr * 64 + m * 16 + lgrp * 4 + r;  // row = b*T + t
          const int bb = gm >> 11, t = gm & 2047;
          out[((size_t)t * B_DIM + bb) * E_DIM + gn] = acc[m][n][r] + bv;
        }
    }
  }
}

// ---------------- flash attention: 32x32 MFMA, mask in registers ------------
// grid (T/128, B*H), 4 waves x 32 q-rows (q = lane&31). Fixed-max softmax.
// __launch_bounds__(256,3): VGPR floor ~150 (round-20: forcing 4 waves spills).
// Round 22: WAITBAR counts vmcnt(4) -- KV DMAs pinned OLDER than the 4 mask
// register loads (sched_barrier between), so the barrier retires exactly KV
// while mask loads stay in flight (compiler's tracked waitcnt covers their
// next-iter use). Mask double-buffered in regs; P in-register via pk_trunc +
// v_permlane32_swap_b32; K/V linear global_load_lds from fragment-permuted
// layouts (zero bank conflicts).
__global__ __launch_bounds__(256, 3) void attn_kernel(
    const unsigned short* __restrict__ Qm, const unsigned short* __restrict__ KPg,
    const unsigned short* __restrict__ VPg, const unsigned short* __restrict__ Mb,
    unsigned short* __restrict__ ctx) {
  __shared__ alignas(16) short Ks[2][4096];
  __shared__ alignas(16) short Vs[2][4096];
  const int tid = threadIdx.x, lane = tid & 63, wave = tid >> 6;
  const int ql = lane & 31, hi = lane >> 5;
  const int bh = blockIdx.y, b = bh >> 4, h = bh & 15;
  const int q0 = blockIdx.x * 128;
  const int qrow = q0 + wave * 32 + ql;

  const size_t base = (size_t)bh * (T_DIM * EHD);
  const uint4* mb4 = (const uint4*)Mb + (size_t)blockIdx.x * 32768 +
                     wave * 256 + lane;  // + tile*1024 + u*64

  bf16x8 qf[4];
#pragma unroll
  for (int i = 0; i < 4; ++i)
    qf[i] = *(const bf16x8*)(Qm + base + (size_t)qrow * 64 + i * 16 + hi * 8);

  f32x16 accO0 = {0.f, 0.f, 0.f, 0.f, 0.f, 0.f, 0.f, 0.f,
                  0.f, 0.f, 0.f, 0.f, 0.f, 0.f, 0.f, 0.f};
  f32x16 accO1 = accO0;
  f32x2 racc2 = {0.f, 0.f};

  uint4 mreg[2][4];  // [tile parity][u = kb*2+half] -- static indices

// KV DMAs first (oldest), then mask reg loads (youngest); order pinned.
#define STAGE(bufi, T_)                                                         \
  {                                                                             \
    _Pragma("unroll") for (int s2 = 0; s2 < 2; ++s2) {                          \
      const int s = wave * 2 + s2;                                              \
      gload16(KPg + base + (size_t)(T_) * 4096 + s * 512 + lane * 8,            \
              &Ks[bufi][s * 512]);                                              \
      gload16(VPg + base + (size_t)(T_) * 4096 + s * 512 + lane * 8,            \
              &Vs[bufi][s * 512]);                                              \
    }                                                                           \
    __builtin_amdgcn_sched_barrier(0);                                          \
    _Pragma("unroll") for (int u = 0; u < 4; ++u) {                             \
      mreg[bufi][u] = mb4[(size_t)(T_) * 1024 + u * 64];                        \
    }                                                                           \
  }

// one mask word -> 2 p values of ACC regs (HALF*8+2W, +1); pack into wk
#define SOFTW(ACC, KB, HALF, W, MW)                                             \
  {                                                                             \
    const f32x2 mm = bfpair1(MW);                                               \
    const f32x2 sv = {ACC[HALF * 8 + 2 * W], ACC[HALF * 8 + 2 * W + 1]};        \
    const f32x2 tt =                                                            \
        __builtin_elementwise_fma(sv, mm, (f32x2){-FMAXC, -FMAXC});             \
    const float p0 = __builtin_amdgcn_exp2f(tt.x);                              \
    const float p1 = __builtin_amdgcn_exp2f(tt.y);                              \
    racc2 += (f32x2){p0, p1};                                                   \
    wk[KB][HALF * 4 + W] = pk_trunc(p0, p1);                                    \
  }

#define SOFTHALF(ACC, KB, HALF, MU)                                             \
  SOFTW(ACC, KB, HALF, 0, (MU).x)                                               \
  SOFTW(ACC, KB, HALF, 1, (MU).y)                                               \
  SOFTW(ACC, KB, HALF, 2, (MU).z)                                               \
  SOFTW(ACC, KB, HALF, 3, (MU).w)

// chunk (KB, HF): build PV B-frag via 2 permlane swaps, 2 MFMAs (dblk 0,1)
#define PVCHUNK(KB, HF)                                                         \
  {                                                                             \
    unsigned a0 = wk[KB][HF * 4 + 0], a1 = wk[KB][HF * 4 + 1];                  \
    unsigned a2 = wk[KB][HF * 4 + 2], a3 = wk[KB][HF * 4 + 3];                  \
    asm("v_permlane32_swap_b32 %0, %1" : "+v"(a0), "+v"(a2));                   \
    asm("v_permlane32_swap_b32 %0, %1" : "+v"(a1), "+v"(a3));                   \
    const u32x4 pw = {a0, a1, a2, a3};                                          \
    const bf16x8 pa = __builtin_bit_cast(bf16x8, pw);                           \
    const bf16x8 vf0 =                                                          \
        *(const bf16x8*)(vb + (0 + (KB)*2 + (HF)) * 512 + lane * 8);            \
    const bf16x8 vf1 =                                                          \
        *(const bf16x8*)(vb + (4 + (KB)*2 + (HF)) * 512 + lane * 8);            \
    accO0 = __builtin_amdgcn_mfma_f32_32x32x16_bf16(vf0, pa, accO0, 0, 0, 0);   \
    accO1 = __builtin_amdgcn_mfma_f32_32x32x16_bf16(vf1, pa, accO1, 0, 0, 0);   \
  }

#define ATTN_ITER(CUR, DO_PRE, TN)                                              \
  {                                                                             \
    if (DO_PRE) {                                                               \
      STAGE((CUR) ^ 1, TN);                                                     \
      __builtin_amdgcn_sched_barrier(0);                                        \
    }                                                                           \
    const short* kbl = Ks[CUR];                                                 \
    const short* vb = Vs[CUR];                                                  \
    f32x16 accS0 = {0.f, 0.f, 0.f, 0.f, 0.f, 0.f, 0.f, 0.f,                     \
                    0.f, 0.f, 0.f, 0.f, 0.f, 0.f, 0.f, 0.f};                    \
    f32x16 accS1 = accS0;                                                       \
    __builtin_amdgcn_s_setprio(1);                                              \
    _Pragma("unroll") for (int i = 0; i < 4; ++i) {                             \
      const bf16x8 kf = *(const bf16x8*)(kbl + i * 512 + lane * 8);             \
      accS0 = __builtin_amdgcn_mfma_f32_32x32x16_bf16(kf, qf[i], accS0, 0, 0, 0); \
    }                                                                           \
    _Pragma("unroll") for (int i = 0; i < 4; ++i) {                             \
      const bf16x8 kf = *(const bf16x8*)(kbl + (4 + i) * 512 + lane * 8);       \
      accS1 = __builtin_amdgcn_mfma_f32_32x32x16_bf16(kf, qf[i], accS1, 0, 0, 0); \
    }                                                                           \
    __builtin_amdgcn_s_setprio(0);                                              \
    unsigned wk[2][8];                                                          \
    SOFTHALF(accS0, 0, 0, mreg[CUR][0])                                         \
    SOFTHALF(accS0, 0, 1, mreg[CUR][1])                                         \
    SOFTHALF(accS1, 1, 0, mreg[CUR][2])                                         \
    SOFTHALF(accS1, 1, 1, mreg[CUR][3])                                         \
    __builtin_amdgcn_s_setprio(1);                                              \
    PVCHUNK(0, 0)                                                               \
    PVCHUNK(0, 1)                                                               \
    PVCHUNK(1, 0)                                                               \
    PVCHUNK(1, 1)                                                               \
    __builtin_amdgcn_s_setprio(0);                                              \
  }

// Retire the 4 KV DMAs (oldest); keep the 4 mask loads in flight across the
// barrier (compiler-tracked waits cover their use next iteration).
#define WAITBAR                                                                 \
  asm volatile("s_waitcnt vmcnt(4)" ::: "memory");                              \
  __builtin_amdgcn_sched_barrier(0);                                            \
  __builtin_amdgcn_s_barrier();                                                 \
  __builtin_amdgcn_sched_barrier(0);

  STAGE(0, 0);
  WAITBAR

  for (int tt = 0; tt < 15; ++tt) {
    ATTN_ITER(0, 1, 2 * tt + 1);
    WAITBAR
    ATTN_ITER(1, 1, 2 * tt + 2);
    WAITBAR
  }
  ATTN_ITER(0, 1, 31);
  WAITBAR
  ATTN_ITER(1, 0, 0);

#undef ATTN_ITER
#undef WAITBAR
#undef STAGE
#undef PVCHUNK
#undef SOFTHALF
#undef SOFTW

  float racc = racc2.x + racc2.y;
  racc += __shfl_xor(racc, 32);
  const float inv = 1.f / racc;
  unsigned short* cp =
      ctx + ((size_t)b * T_DIM + qrow) * E_DIM + h * 64 + hi * 4;
#define EPI(ACC, DBLK)                                                          \
  _Pragma("unroll") for (int rg = 0; rg < 4; ++rg) {                            \
    uint2 w;                                                                    \
    w.x = pkbf(ACC[rg * 4 + 0] * inv, ACC[rg * 4 + 1] * inv);                   \
    w.y = pkbf(ACC[rg * 4 + 2] * inv, ACC[rg * 4 + 3] * inv);                   \
    *(uint2*)(cp + (DBLK)*32 + rg * 8) = w;                                     \
  }
  EPI(accO0, 0)
  EPI(accO1, 1)
#undef EPI
}

extern "C" void kernel_launch(void* const* d_in, const int* in_sizes, int n_in,
                              void* d_out, int out_size, void* d_ws, size_t ws_size,
                              hipStream_t stream) {
  const float* q    = (const float*)d_in[0];
  const float* k    = (const float*)d_in[1];
  const float* v    = (const float*)d_in[2];
  const float* mask = (const float*)d_in[3];
  const float* wqkv = (const float*)d_in[4];
  const float* bqkv = (const float*)d_in[5];
  const float* wout = (const float*)d_in[6];
  const float* bout = (const float*)d_in[7];

  char* ws = (char*)d_ws;
  unsigned short* Xb   = (unsigned short*)(ws);
  unsigned short* Wqb  = (unsigned short*)(ws + 50331648);
  unsigned short* Wob  = (unsigned short*)(ws + 56623104);
  unsigned short* QKVb = (unsigned short*)(ws + 58720256);  // [Q|KP|VP] bf16
  unsigned short* CTXb = (unsigned short*)(ws);             // [B][T][E] (Xb dead)
  unsigned short* Mb   = (unsigned short*)(ws + 16777216);  // permuted bf16 mask

  cvt_fused<<<2048, 256, 0, stream>>>(
      (const float4*)q, (const float4*)k, (const float4*)v,
      (const float4*)wqkv, (const float4*)wout, (uint2*)Xb,
      (uint2*)(Xb + 8388608), (uint2*)(Xb + 16777216), (uint2*)Wqb,
      (uint2*)Wob);

  gemm_kernel<0><<<dim3(64, 24), 256, 0, stream>>>(Xb, Wqb, bqkv, QKVb, 1024);
  // mask -> permuted bf16 AFTER GEMM1 (Mb lives in the then-dead Xb region)
  mask_perm<<<2048, 256, 0, stream>>>(mask, (uint2*)Mb);
  attn_kernel<<<dim3(16, 64), 256, 0, stream>>>(QKVb, QKVb + 8388608,
                                                QKVb + 16777216, Mb, CTXb);
  gemm_kernel<1><<<dim3(64, 8), 256, 0, stream>>>(CTXb, Wob, bout, d_out, 1024);
}